// Round 1
// baseline (39.957 us; speedup 1.0000x reference)
//
#include <hip/hip_runtime.h>

// TopKRouter: x (4,8192,1024) f32, W (8,1024) f32
// out = [router_output (4,8192,8) f32 | top_idx (4,8192,2) written as f32 values]

constexpr int Cc = 1024;
constexpr int Ec = 8;
constexpr int TOKENS = 4 * 8192;          // 32768
constexpr int TPW = 4;                    // tokens per wave
constexpr int WPB = 4;                    // waves per block
constexpr int BLOCK = WPB * 64;           // 256
constexpr int TPB = TPW * WPB;            // 16 tokens per block
constexpr int GRID = TOKENS / TPB;        // 2048

__global__ __launch_bounds__(BLOCK) void topk_router_kernel(
    const float* __restrict__ x, const float* __restrict__ W, float* __restrict__ out)
{
    __shared__ float Ws[Ec * Cc];         // 32 KB
    const int tid = threadIdx.x;

    // Cooperative W load: 8192 floats = 2048 float4; 256 threads x 8
    {
        const float4* Wg4 = reinterpret_cast<const float4*>(W);
        float4* Ws4 = reinterpret_cast<float4*>(Ws);
        #pragma unroll
        for (int i = 0; i < (Ec * Cc / 4) / BLOCK; ++i)
            Ws4[tid + i * BLOCK] = Wg4[tid + i * BLOCK];
    }
    __syncthreads();

    const int lane = tid & 63;
    const int wave = tid >> 6;
    const int t0 = (blockIdx.x * WPB + wave) * TPW;

    float acc[TPW][Ec];
    #pragma unroll
    for (int t = 0; t < TPW; ++t)
        #pragma unroll
        for (int e = 0; e < Ec; ++e) acc[t][e] = 0.f;

    const float* xp = x + (size_t)t0 * Cc;

    #pragma unroll
    for (int it = 0; it < Cc / 256; ++it) {       // 4 chunks of 256 floats
        const int cb = it * 256 + lane * 4;
        float4 xv[TPW];
        #pragma unroll
        for (int t = 0; t < TPW; ++t)
            xv[t] = *reinterpret_cast<const float4*>(xp + (size_t)t * Cc + cb);
        #pragma unroll
        for (int e = 0; e < Ec; ++e) {
            float4 wv = *reinterpret_cast<const float4*>(&Ws[e * Cc + cb]);
            #pragma unroll
            for (int t = 0; t < TPW; ++t) {
                acc[t][e] += xv[t].x * wv.x;
                acc[t][e] += xv[t].y * wv.y;
                acc[t][e] += xv[t].z * wv.z;
                acc[t][e] += xv[t].w * wv.w;
            }
        }
    }

    // Full-wave butterfly reduction: every lane ends with the complete sums
    #pragma unroll
    for (int s = 1; s < 64; s <<= 1)
        #pragma unroll
        for (int t = 0; t < TPW; ++t)
            #pragma unroll
            for (int e = 0; e < Ec; ++e)
                acc[t][e] += __shfl_xor(acc[t][e], s, 64);

    // Epilogue: uniform compute, lanes 0..TPW-1 each store one token
    float* outIdx = out + (size_t)TOKENS * Ec;
    #pragma unroll
    for (int t = 0; t < TPW; ++t) {
        float m = acc[t][0];
        #pragma unroll
        for (int e = 1; e < Ec; ++e) m = fmaxf(m, acc[t][e]);
        float p[Ec];
        float ssum = 0.f;
        #pragma unroll
        for (int e = 0; e < Ec; ++e) { p[e] = __expf(acc[t][e] - m); ssum += p[e]; }
        const float inv = 1.0f / ssum;
        #pragma unroll
        for (int e = 0; e < Ec; ++e) p[e] *= inv;

        // top-1: strict > ascending -> lowest index on ties (matches lax.top_k)
        int i1 = 0; float v1 = p[0];
        #pragma unroll
        for (int e = 1; e < Ec; ++e) { if (p[e] > v1) { v1 = p[e]; i1 = e; } }
        // top-2: skip i1, strict > ascending
        int i2 = -1; float v2 = -1.f;
        #pragma unroll
        for (int e = 0; e < Ec; ++e) { if (e != i1 && p[e] > v2) { v2 = p[e]; i2 = e; } }

        if (lane == t) {
            float r[8];
            #pragma unroll
            for (int e = 0; e < Ec; ++e)
                r[e] = (e == i1) ? v1 : ((e == i2) ? v2 : 0.f);
            float4* o4 = reinterpret_cast<float4*>(out + (size_t)(t0 + t) * Ec);
            o4[0] = make_float4(r[0], r[1], r[2], r[3]);
            o4[1] = make_float4(r[4], r[5], r[6], r[7]);
            float2* oi = reinterpret_cast<float2*>(outIdx + (size_t)(t0 + t) * 2);
            *oi = make_float2((float)i1, (float)i2);
        }
    }
}

extern "C" void kernel_launch(void* const* d_in, const int* in_sizes, int n_in,
                              void* d_out, int out_size, void* d_ws, size_t ws_size,
                              hipStream_t stream) {
    const float* x = (const float*)d_in[0];
    const float* W = (const float*)d_in[1];
    float* out = (float*)d_out;
    hipLaunchKernelGGL(topk_router_kernel, dim3(GRID), dim3(BLOCK), 0, stream,
                       x, W, out);
}